// Round 5
// baseline (163.785 us; speedup 1.0000x reference)
//
#include <hip/hip_runtime.h>
#include <hip/hip_bf16.h>

typedef __attribute__((ext_vector_type(8))) __bf16 bf16x8;
typedef __attribute__((ext_vector_type(4))) __bf16 bf16x4;
typedef __attribute__((ext_vector_type(4))) float  f32x4;

#define MFMA16(a, b, c) __builtin_amdgcn_mfma_f32_16x16x32_bf16((a), (b), (c), 0, 0, 0)

// B=2, S=4096, D=256, P=R=64. Flattened rows g = b*4096 + n (8192 total).
static constexpr size_t OFF_WVT = 0;                         // bf16 [256][256] ([n][k])
static constexpr size_t OFF_WLT = OFF_WVT + 256 * 256 * 2;   // bf16 [64][256]
static constexpr size_t OFF_WRT = OFF_WLT + 64 * 256 * 2;    // bf16 [64][256]
static constexpr size_t OFF_WOT = OFF_WRT + 64 * 256 * 2;    // bf16 [256][256]
static constexpr size_t OFF_VT  = 1u << 20;                  // bf16 [2][64][8][256][8] packed V, 4 MiB
static constexpr size_t OFF_L   = 6u << 20;                  // f32  [8192][64]  2 MiB
static constexpr size_t OFF_R   = 8u << 20;                  // f32  [8192][64]  2 MiB

__device__ __forceinline__ float fast_exp2(float x) {
  float e;
  asm("v_exp_f32 %0, %1" : "=v"(e) : "v"(x));
  return e;
}

__device__ __forceinline__ bf16x8 cvt8(float4 a, float4 b) {
  bf16x8 o;
  o[0] = (__bf16)a.x; o[1] = (__bf16)a.y; o[2] = (__bf16)a.z; o[3] = (__bf16)a.w;
  o[4] = (__bf16)b.x; o[5] = (__bf16)b.y; o[6] = (__bf16)b.z; o[7] = (__bf16)b.w;
  return o;
}

// --------------------------------------------- weight transpose to [n][k] bf16
__global__ __launch_bounds__(256) void k_prepw(const float* __restrict__ Wv,
                                               const float* __restrict__ Wl,
                                               const float* __restrict__ Wr,
                                               const float* __restrict__ Wo,
                                               __bf16* __restrict__ Wvt,
                                               __bf16* __restrict__ Wlt,
                                               __bf16* __restrict__ Wrt,
                                               __bf16* __restrict__ Wot) {
  const int idx = blockIdx.x * 256 + threadIdx.x;  // 0 .. 163839
  if (idx < 65536) {
    const int k = idx >> 8, n = idx & 255;
    Wvt[n * 256 + k] = (__bf16)Wv[idx];
  } else if (idx < 81920) {
    const int j = idx - 65536;
    const int k = j >> 6, n = j & 63;
    Wlt[n * 256 + k] = (__bf16)Wl[j];
  } else if (idx < 98304) {
    const int j = idx - 81920;
    const int k = j >> 6, n = j & 63;
    Wrt[n * 256 + k] = (__bf16)Wr[j];
  } else {
    const int j = idx - 98304;
    const int k = j >> 8, n = j & 255;
    Wot[n * 256 + k] = (__bf16)Wo[j];
  }
}

// --------- projections: V packed [bat][mc][m8][d][j] (bf16), l, r (fp32)
// grid (128, 6): x = 64-row block; y: 0..3 Wv d-tiles, 4 -> Wl, 5 -> Wr
__global__ __launch_bounds__(256) void k_proj(const float* __restrict__ x,
                                              const __bf16* __restrict__ Wvt,
                                              const __bf16* __restrict__ Wlt,
                                              const __bf16* __restrict__ Wrt,
                                              __bf16* __restrict__ Vt,
                                              float* __restrict__ lbuf,
                                              float* __restrict__ rbuf) {
  __shared__ __align__(16) __bf16 vs[8 * 64 * 8];  // [m8][d_local][j]
  const int t = threadIdx.x;
  const int lane = t & 63, wave = t >> 6;
  const int l16 = lane & 15, quad = lane >> 4;
  const int wr = wave >> 1, wc = wave & 1;
  const int rbk = blockIdx.x;
  const int ct  = blockIdx.y;
  const __bf16* Wt;
  int colbase;
  if (ct < 4)       { Wt = Wvt; colbase = ct * 64; }
  else if (ct == 4) { Wt = Wlt; colbase = 0; }
  else              { Wt = Wrt; colbase = 0; }
  const int row0 = rbk * 64 + wr * 32;
  const int c0   = colbase + wc * 32;
  f32x4 acc[2][2] = {};
  for (int kk = 0; kk < 256; kk += 32) {
    const int ko = kk + quad * 8;
    const float* xr0 = x + (size_t)(row0 + l16) * 256 + ko;
    const float* xr1 = x + (size_t)(row0 + 16 + l16) * 256 + ko;
    bf16x8 a0 = cvt8(*(const float4*)xr0, *(const float4*)(xr0 + 4));
    bf16x8 a1 = cvt8(*(const float4*)xr1, *(const float4*)(xr1 + 4));
    bf16x8 b0 = *(const bf16x8*)(Wt + (size_t)(c0 + l16) * 256 + ko);
    bf16x8 b1 = *(const bf16x8*)(Wt + (size_t)(c0 + 16 + l16) * 256 + ko);
    acc[0][0] = MFMA16(a0, b0, acc[0][0]);
    acc[0][1] = MFMA16(a0, b1, acc[0][1]);
    acc[1][0] = MFMA16(a1, b0, acc[1][0]);
    acc[1][1] = MFMA16(a1, b1, acc[1][1]);
  }
  if (ct < 4) {
#pragma unroll
    for (int mt = 0; mt < 2; ++mt)
#pragma unroll
      for (int nt = 0; nt < 2; ++nt) {
        const int m8 = wr * 4 + mt * 2 + (quad >> 1);
        const int d  = wc * 32 + nt * 16 + l16;
        bf16x4 o;
        o.x = (__bf16)acc[mt][nt][0];
        o.y = (__bf16)acc[mt][nt][1];
        o.z = (__bf16)acc[mt][nt][2];
        o.w = (__bf16)acc[mt][nt][3];
        *(bf16x4*)(&vs[m8 * 512 + d * 8 + (quad & 1) * 4]) = o;
      }
    __syncthreads();
    const int m8 = t >> 5, s32 = t & 31;
    const int bat = rbk >> 6, mc = rbk & 63;
    bf16x8 a = *(const bf16x8*)(&vs[m8 * 512 + s32 * 16]);
    bf16x8 b = *(const bf16x8*)(&vs[m8 * 512 + s32 * 16 + 8]);
    __bf16* dst = Vt + (size_t)bat * 1048576 + (size_t)mc * 16384 +
                  m8 * 2048 + ct * 512 + s32 * 16;
    *(bf16x8*)dst       = a;
    *(bf16x8*)(dst + 8) = b;
  } else {
    float* dstb = (ct == 4) ? lbuf : rbuf;
#pragma unroll
    for (int mt = 0; mt < 2; ++mt)
#pragma unroll
      for (int nt = 0; nt < 2; ++nt) {
        const int col = c0 + nt * 16 + l16;
        const int gr  = rbk * 64 + wr * 32 + mt * 16 + quad * 4;
#pragma unroll
        for (int rr = 0; rr < 4; ++rr)
          dstb[(size_t)(gr + rr) * 64 + col] = acc[mt][nt][rr];
      }
  }
}

// ---- consolidated attention: softmax(P)@V (+exact Z) + fused @Wo epilogue
// grid (256): TM=32, TN=256. 4 waves, each owns a private K-span of 1024.
// No __syncthreads in the main loop; B-frags direct from global (L2), reg dbuf.
#define VP(S, NT) (Vbase + (size_t)((w * 16 + ((S) >> 1)) * 16384 + \
                   (((S)&1) * 4 + quad) * 2048 + ((NT)*16 + l16) * 8))
__global__ __launch_bounds__(256, 1) void k_attn(const float* __restrict__ lbuf,
                                                 const float* __restrict__ rbuf,
                                                 const __bf16* __restrict__ Vt,
                                                 const __bf16* __restrict__ Wot,
                                                 float* __restrict__ out) {
  __shared__ __align__(16) float bufA[256 * 36];   // C^T partial [col][row], pad 36
  __shared__ __align__(16) float bufB[256 * 36];
  __shared__ float zbuf[4][32];
  __shared__ float zinv[32];
  __shared__ __align__(16) __bf16 obuf[32 * 264];  // normalized o_pre [row][k]
  const int t = threadIdx.x;
  const int lane = t & 63, w = t >> 6;
  const int l16 = lane & 15, quad = lane >> 4;
  const int rb = blockIdx.x;
  const int g0 = rb * 32;
  const int bat = rb >> 7;
  const __bf16* Vbase = Vt + (size_t)bat * 1048576;
  const float LOG2E = 1.44269504088896f;

  // r frags (pre-scaled by log2e) and l values for this wave's K-span
  float rreg[2][16], lreg[2][16];
#pragma unroll
  for (int mt = 0; mt < 2; ++mt) {
    const float* rp = rbuf + (size_t)(g0 + mt * 16 + l16) * 64;
    f32x4 a = *(const f32x4*)(rp + quad * 8);
    f32x4 b = *(const f32x4*)(rp + quad * 8 + 4);
    f32x4 c = *(const f32x4*)(rp + 32 + quad * 8);
    f32x4 d = *(const f32x4*)(rp + 32 + quad * 8 + 4);
#pragma unroll
    for (int j = 0; j < 4; ++j) {
      rreg[mt][j]      = a[j] * LOG2E;
      rreg[mt][4 + j]  = b[j] * LOG2E;
      rreg[mt][8 + j]  = c[j] * LOG2E;
      rreg[mt][12 + j] = d[j] * LOG2E;
    }
    const float* lp = lbuf + (size_t)(g0 + mt * 16 + l16) * 64 + w * 16;
    f32x4 e = *(const f32x4*)(lp);
    f32x4 f = *(const f32x4*)(lp + 4);
    f32x4 g = *(const f32x4*)(lp + 8);
    f32x4 h = *(const f32x4*)(lp + 12);
#pragma unroll
    for (int j = 0; j < 4; ++j) {
      lreg[mt][j]      = e[j];
      lreg[mt][4 + j]  = f[j];
      lreg[mt][8 + j]  = g[j];
      lreg[mt][12 + j] = h[j];
    }
  }

  f32x4 acc[2][16] = {};
  float zacc0 = 0.f, zacc1 = 0.f;
  bf16x8 bvA[16], bvB[16];

#pragma unroll
  for (int nt = 0; nt < 16; ++nt) bvA[nt] = *(const bf16x8*)VP(0, nt);

  for (int sh = 0; sh < 16; ++sh) {
    const float lv0 = lreg[0][sh], lv1 = lreg[1][sh];
    // prefetch odd step s=2sh+1 while computing even step
#pragma unroll
    for (int nt = 0; nt < 16; ++nt) bvB[nt] = *(const bf16x8*)VP(2 * sh + 1, nt);
    {
      bf16x8 af0, af1;
#pragma unroll
      for (int j = 0; j < 8; ++j) {
        const float e0 = fast_exp2(lv0 * rreg[0][j]);
        const float e1 = fast_exp2(lv1 * rreg[1][j]);
        zacc0 += e0; zacc1 += e1;
        af0[j] = (__bf16)e0; af1[j] = (__bf16)e1;
      }
#pragma unroll
      for (int nt = 0; nt < 16; ++nt) {
        acc[0][nt] = MFMA16(af0, bvA[nt], acc[0][nt]);
        acc[1][nt] = MFMA16(af1, bvA[nt], acc[1][nt]);
      }
    }
    // prefetch next even step (sh=15 reads harmless slack inside ws)
#pragma unroll
    for (int nt = 0; nt < 16; ++nt) bvA[nt] = *(const bf16x8*)VP(2 * sh + 2, nt);
    {
      bf16x8 af0, af1;
#pragma unroll
      for (int j = 0; j < 8; ++j) {
        const float e0 = fast_exp2(lv0 * rreg[0][8 + j]);
        const float e1 = fast_exp2(lv1 * rreg[1][8 + j]);
        zacc0 += e0; zacc1 += e1;
        af0[j] = (__bf16)e0; af1[j] = (__bf16)e1;
      }
#pragma unroll
      for (int nt = 0; nt < 16; ++nt) {
        acc[0][nt] = MFMA16(af0, bvB[nt], acc[0][nt]);
        acc[1][nt] = MFMA16(af1, bvB[nt], acc[1][nt]);
      }
    }
  }

  // per-wave Z partial (reduce over quads; rows = l16 / 16+l16)
  {
    float z0 = zacc0, z1 = zacc1;
    z0 += __shfl_xor(z0, 16); z0 += __shfl_xor(z0, 32);
    z1 += __shfl_xor(z1, 16); z1 += __shfl_xor(z1, 32);
    if (quad == 0) { zbuf[w][l16] = z0; zbuf[w][16 + l16] = z1; }
  }

  // cross-wave C reduction: waves 0/1 write bufA/bufB; waves 2/3 add in
  if (w < 2) {
    float* bx = w ? bufB : bufA;
#pragma unroll
    for (int mt = 0; mt < 2; ++mt)
#pragma unroll
      for (int nt = 0; nt < 16; ++nt)
        *(f32x4*)&bx[(nt * 16 + l16) * 36 + mt * 16 + quad * 4] = acc[mt][nt];
  }
  __syncthreads();
  if (w >= 2) {
    float* bx = (w == 3) ? bufB : bufA;
#pragma unroll
    for (int mt = 0; mt < 2; ++mt)
#pragma unroll
      for (int nt = 0; nt < 16; ++nt) {
        f32x4* p = (f32x4*)&bx[(nt * 16 + l16) * 36 + mt * 16 + quad * 4];
        f32x4 v = *p;
        v += acc[mt][nt];
        *p = v;
      }
  } else if (t < 32) {
    zinv[t] = 1.0f / (zbuf[0][t] + zbuf[1][t] + zbuf[2][t] + zbuf[3][t]);
  }
  __syncthreads();

  // sum A+B, normalize, store bf16 o_pre tile [row][k]
  {
    const int c = t;
#pragma unroll
    for (int i = 0; i < 8; ++i) {
      f32x4 v = *(const f32x4*)&bufA[c * 36 + i * 4];
      f32x4 u = *(const f32x4*)&bufB[c * 36 + i * 4];
#pragma unroll
      for (int jj = 0; jj < 4; ++jj) {
        const int row = i * 4 + jj;
        obuf[row * 264 + c] = (__bf16)((v[jj] + u[jj]) * zinv[row]);
      }
    }
  }
  __syncthreads();

  // fused output GEMM: out[g0..g0+31][:] = o_pre @ Wo (fp32)
  const int wcol = w * 64;
  f32x4 oacc[2][4] = {};
#pragma unroll
  for (int kc = 0; kc < 8; ++kc) {
    const int k0 = kc * 32 + quad * 8;
    bf16x8 a0 = *(const bf16x8*)&obuf[l16 * 264 + k0];
    bf16x8 a1 = *(const bf16x8*)&obuf[(16 + l16) * 264 + k0];
#pragma unroll
    for (int nt = 0; nt < 4; ++nt) {
      bf16x8 bv = *(const bf16x8*)(Wot + (size_t)(wcol + nt * 16 + l16) * 256 + k0);
      oacc[0][nt] = MFMA16(a0, bv, oacc[0][nt]);
      oacc[1][nt] = MFMA16(a1, bv, oacc[1][nt]);
    }
  }
#pragma unroll
  for (int mt = 0; mt < 2; ++mt)
#pragma unroll
    for (int nt = 0; nt < 4; ++nt) {
      const int col = wcol + nt * 16 + l16;
      const int r0  = g0 + mt * 16 + quad * 4;
#pragma unroll
      for (int rr = 0; rr < 4; ++rr)
        out[(size_t)(r0 + rr) * 256 + col] = oacc[mt][nt][rr];
    }
}

extern "C" void kernel_launch(void* const* d_in, const int* in_sizes, int n_in,
                              void* d_out, int out_size, void* d_ws, size_t ws_size,
                              hipStream_t stream) {
  const float* x  = (const float*)d_in[0];
  const float* Wl = (const float*)d_in[1];
  const float* Wr = (const float*)d_in[2];
  const float* Wv = (const float*)d_in[3];
  const float* Wo = (const float*)d_in[4];
  char* ws = (char*)d_ws;
  __bf16* Wvt = (__bf16*)(ws + OFF_WVT);
  __bf16* Wlt = (__bf16*)(ws + OFF_WLT);
  __bf16* Wrt = (__bf16*)(ws + OFF_WRT);
  __bf16* Wot = (__bf16*)(ws + OFF_WOT);
  __bf16* Vt  = (__bf16*)(ws + OFF_VT);
  float*  lb  = (float*)(ws + OFF_L);
  float*  rbf = (float*)(ws + OFF_R);
  float*  out = (float*)d_out;

  k_prepw<<<640, 256, 0, stream>>>(Wv, Wl, Wr, Wo, Wvt, Wlt, Wrt, Wot);
  k_proj<<<dim3(128, 6), 256, 0, stream>>>(x, Wvt, Wlt, Wrt, Vt, lb, rbf);
  k_attn<<<256, 256, 0, stream>>>(lb, rbf, Vt, Wot, out);
}

// Round 6
// 136.240 us; speedup vs baseline: 1.2022x; 1.2022x over previous
//
#include <hip/hip_runtime.h>
#include <hip/hip_bf16.h>

typedef __attribute__((ext_vector_type(8))) __bf16 bf16x8;
typedef __attribute__((ext_vector_type(4))) __bf16 bf16x4;
typedef __attribute__((ext_vector_type(4))) float  f32x4;

#define MFMA16(a, b, c) __builtin_amdgcn_mfma_f32_16x16x32_bf16((a), (b), (c), 0, 0, 0)

// B=2, S=4096, D=256, P=R=64. Flattened rows g = b*4096 + n (8192 total).
static constexpr size_t OFF_WVT  = 0;                        // bf16 [256][256] ([n][k])
static constexpr size_t OFF_WLT  = OFF_WVT + 256 * 256 * 2;  // bf16 [64][256]
static constexpr size_t OFF_WRT  = OFF_WLT + 64 * 256 * 2;   // bf16 [64][256]
static constexpr size_t OFF_WOT  = OFF_WRT + 64 * 256 * 2;   // bf16 [256][256]
static constexpr size_t OFF_VT   = 1u << 20;                 // bf16 [2][64][8][256][8] packed V, 4 MiB
static constexpr size_t OFF_L    = 6u << 20;                 // f32  [8192][64]  2 MiB
static constexpr size_t OFF_R    = 8u << 20;                 // f32  [8192][64]  2 MiB
static constexpr size_t OFF_PART = 10u << 20;                // bf16 [4][8192][256] 16 MiB (pre-Wo partials)
static constexpr size_t OFF_ZP   = 26u << 20;                // f32  [4][8192]   128 KiB

__device__ __forceinline__ float fast_exp2(float x) {
  float e;
  asm("v_exp_f32 %0, %1" : "=v"(e) : "v"(x));
  return e;
}

__device__ __forceinline__ bf16x8 cvt8(float4 a, float4 b) {
  bf16x8 o;
  o[0] = (__bf16)a.x; o[1] = (__bf16)a.y; o[2] = (__bf16)a.z; o[3] = (__bf16)a.w;
  o[4] = (__bf16)b.x; o[5] = (__bf16)b.y; o[6] = (__bf16)b.z; o[7] = (__bf16)b.w;
  return o;
}

// --------------------------------------------- weight transpose to [n][k] bf16
__global__ __launch_bounds__(256) void k_prepw(const float* __restrict__ Wv,
                                               const float* __restrict__ Wl,
                                               const float* __restrict__ Wr,
                                               const float* __restrict__ Wo,
                                               __bf16* __restrict__ Wvt,
                                               __bf16* __restrict__ Wlt,
                                               __bf16* __restrict__ Wrt,
                                               __bf16* __restrict__ Wot) {
  const int idx = blockIdx.x * 256 + threadIdx.x;  // 0 .. 163839
  if (idx < 65536) {
    const int k = idx >> 8, n = idx & 255;
    Wvt[n * 256 + k] = (__bf16)Wv[idx];
  } else if (idx < 81920) {
    const int j = idx - 65536;
    const int k = j >> 6, n = j & 63;
    Wlt[n * 256 + k] = (__bf16)Wl[j];
  } else if (idx < 98304) {
    const int j = idx - 81920;
    const int k = j >> 6, n = j & 63;
    Wrt[n * 256 + k] = (__bf16)Wr[j];
  } else {
    const int j = idx - 98304;
    const int k = j >> 8, n = j & 255;
    Wot[n * 256 + k] = (__bf16)Wo[j];
  }
}

// --------- projections: V packed [bat][chunk][m8][d][j] (bf16), l, r (fp32)
// grid (128, 6): x = 64-row block; y: 0..3 Wv d-tiles, 4 -> Wl, 5 -> Wr
__global__ __launch_bounds__(256) void k_proj(const float* __restrict__ x,
                                              const __bf16* __restrict__ Wvt,
                                              const __bf16* __restrict__ Wlt,
                                              const __bf16* __restrict__ Wrt,
                                              __bf16* __restrict__ Vt,
                                              float* __restrict__ lbuf,
                                              float* __restrict__ rbuf) {
  __shared__ __align__(16) __bf16 vs[8 * 64 * 8];  // [m8][d_local][j]
  const int t = threadIdx.x;
  const int lane = t & 63, wave = t >> 6;
  const int l16 = lane & 15, quad = lane >> 4;
  const int wr = wave >> 1, wc = wave & 1;
  const int rbk = blockIdx.x;
  const int ct  = blockIdx.y;
  const __bf16* Wt;
  int colbase;
  if (ct < 4)       { Wt = Wvt; colbase = ct * 64; }
  else if (ct == 4) { Wt = Wlt; colbase = 0; }
  else              { Wt = Wrt; colbase = 0; }
  const int row0 = rbk * 64 + wr * 32;
  const int c0   = colbase + wc * 32;
  f32x4 acc[2][2] = {};
  for (int kk = 0; kk < 256; kk += 32) {
    const int ko = kk + quad * 8;
    const float* xr0 = x + (size_t)(row0 + l16) * 256 + ko;
    const float* xr1 = x + (size_t)(row0 + 16 + l16) * 256 + ko;
    bf16x8 a0 = cvt8(*(const float4*)xr0, *(const float4*)(xr0 + 4));
    bf16x8 a1 = cvt8(*(const float4*)xr1, *(const float4*)(xr1 + 4));
    bf16x8 b0 = *(const bf16x8*)(Wt + (size_t)(c0 + l16) * 256 + ko);
    bf16x8 b1 = *(const bf16x8*)(Wt + (size_t)(c0 + 16 + l16) * 256 + ko);
    acc[0][0] = MFMA16(a0, b0, acc[0][0]);
    acc[0][1] = MFMA16(a0, b1, acc[0][1]);
    acc[1][0] = MFMA16(a1, b0, acc[1][0]);
    acc[1][1] = MFMA16(a1, b1, acc[1][1]);
  }
  if (ct < 4) {
#pragma unroll
    for (int mt = 0; mt < 2; ++mt)
#pragma unroll
      for (int nt = 0; nt < 2; ++nt) {
        const int m8 = wr * 4 + mt * 2 + (quad >> 1);
        const int d  = wc * 32 + nt * 16 + l16;
        bf16x4 o;
        o.x = (__bf16)acc[mt][nt][0];
        o.y = (__bf16)acc[mt][nt][1];
        o.z = (__bf16)acc[mt][nt][2];
        o.w = (__bf16)acc[mt][nt][3];
        *(bf16x4*)(&vs[m8 * 512 + d * 8 + (quad & 1) * 4]) = o;
      }
    __syncthreads();
    const int m8 = t >> 5, s32 = t & 31;
    const int bat = rbk >> 6, mc = rbk & 63;
    bf16x8 a = *(const bf16x8*)(&vs[m8 * 512 + s32 * 16]);
    bf16x8 b = *(const bf16x8*)(&vs[m8 * 512 + s32 * 16 + 8]);
    __bf16* dst = Vt + (size_t)bat * 1048576 + (size_t)mc * 16384 +
                  m8 * 2048 + ct * 512 + s32 * 16;
    *(bf16x8*)dst       = a;
    *(bf16x8*)(dst + 8) = b;
  } else {
    float* dstb = (ct == 4) ? lbuf : rbuf;
#pragma unroll
    for (int mt = 0; mt < 2; ++mt)
#pragma unroll
      for (int nt = 0; nt < 2; ++nt) {
        const int col = c0 + nt * 16 + l16;
        const int gr  = rbk * 64 + wr * 32 + mt * 16 + quad * 4;
#pragma unroll
        for (int rr = 0; rr < 4; ++rr)
          dstb[(size_t)(gr + rr) * 64 + col] = acc[mt][nt][rr];
      }
  }
}

// ---------------- main attention GEMM: part_s = P_s @ V (unnormalized), Z_s
// grid (64, 4): TM=128, TN=256, split-K=4 (k-span 1024 = 16 chunks of 64).
// 512 threads = 8 waves: 4 row-waves (32 rows, mt=2) x 2 col-waves (128 cols, nt=8).
// m97-style staging: global->VGPR at iter top, ds_write after MFMA phase,
// true double-buffer, ONE barrier per iteration (no DMA drain).
__global__ __launch_bounds__(512, 2) void k_attn(const float* __restrict__ lbuf,
                                                 const float* __restrict__ rbuf,
                                                 const __bf16* __restrict__ Vt,
                                                 __bf16* __restrict__ part,
                                                 float* __restrict__ zpart) {
  __shared__ __align__(16) char smem[74240];   // vt[2][32KB] + ls[128][17]f32 ; epi ctile aliases
  __bf16* vt0 = (__bf16*)smem;
  __bf16* vt1 = (__bf16*)(smem + 32768);
  float*  ls  = (float*)(smem + 65536);        // [128][17]
  const int t = threadIdx.x;                   // 0..511
  const int lane = t & 63, w = t >> 6;
  const int l16 = lane & 15, quad = lane >> 4;
  const int wr = w >> 1, wc = w & 1;           // 4 row-waves x 2 col-waves
  const int rb = blockIdx.x;                   // 0..63
  const int sp = blockIdx.y;                   // 0..3
  const int g0 = rb * 128;
  const int bat = rb >> 5;
  const __bf16* Vbase = Vt + (size_t)bat * 1048576;
  const int ck0 = sp * 16;                     // first 64k-chunk of this split

  // l tile: rows g0..+127, chunk-cols ck0..+15 (stride 17, conflict-free reads)
  {
    const int idx = t * 4;
    const int row = idx >> 4, c = idx & 15;
    f32x4 v = *(const f32x4*)(lbuf + (size_t)(g0 + row) * 64 + ck0 + c);
    ls[row * 17 + c + 0] = v[0];
    ls[row * 17 + c + 1] = v[1];
    ls[row * 17 + c + 2] = v[2];
    ls[row * 17 + c + 3] = v[3];
  }
  // r fragments pre-scaled by log2(e): rreg[mt][kk*8+j] = r[row][kk*32+quad*8+j]
  const float LOG2E = 1.44269504088896f;
  float rreg[2][16];
#pragma unroll
  for (int mt = 0; mt < 2; ++mt) {
    const float* rp = rbuf + (size_t)(g0 + wr * 32 + mt * 16 + l16) * 64;
    f32x4 a = *(const f32x4*)(rp + quad * 8);
    f32x4 b = *(const f32x4*)(rp + quad * 8 + 4);
    f32x4 c = *(const f32x4*)(rp + 32 + quad * 8);
    f32x4 d = *(const f32x4*)(rp + 32 + quad * 8 + 4);
#pragma unroll
    for (int j = 0; j < 4; ++j) {
      rreg[mt][j]      = a[j] * LOG2E;
      rreg[mt][4 + j]  = b[j] * LOG2E;
      rreg[mt][8 + j]  = c[j] * LOG2E;
      rreg[mt][12 + j] = d[j] * LOG2E;
    }
  }

  f32x4 acc[2][8] = {};
  float zacc[2] = {0.f, 0.f};
  bf16x8 stg[4];

  // stage chunk 0 into vt0 (32 KB: 512 threads x 4 x 16 B, linear)
  {
    const __bf16* src = Vbase + (size_t)ck0 * 16384;
#pragma unroll
    for (int i = 0; i < 4; ++i) stg[i] = *(const bf16x8*)(src + (size_t)(i * 512 + t) * 8);
#pragma unroll
    for (int i = 0; i < 4; ++i) *(bf16x8*)(vt0 + (i * 512 + t) * 8) = stg[i];
  }
  __syncthreads();

  for (int kc = 0; kc < 16; ++kc) {
    __bf16* cur = (kc & 1) ? vt1 : vt0;
    __bf16* nxt = (kc & 1) ? vt0 : vt1;
    // issue next chunk's global loads (latency hides under exp+MFMA phase)
    if (kc < 15) {
      const __bf16* src = Vbase + (size_t)(ck0 + kc + 1) * 16384;
#pragma unroll
      for (int i = 0; i < 4; ++i) stg[i] = *(const bf16x8*)(src + (size_t)(i * 512 + t) * 8);
    }
    // A-fragments of P for this chunk, in registers (single v_exp per element)
    bf16x8 af[2][2];
#pragma unroll
    for (int mt = 0; mt < 2; ++mt) {
      const float lv = ls[(wr * 32 + mt * 16 + l16) * 17 + kc];
#pragma unroll
      for (int kk = 0; kk < 2; ++kk)
#pragma unroll
        for (int j = 0; j < 8; ++j) {
          const float e = fast_exp2(lv * rreg[mt][kk * 8 + j]);
          zacc[mt] += e;
          af[mt][kk][j] = (__bf16)e;
        }
    }
    // MFMA phase: each B-read feeds 2 MFMAs (mt=2)
#pragma unroll
    for (int kk = 0; kk < 2; ++kk)
#pragma unroll
      for (int nt = 0; nt < 8; ++nt) {
        bf16x8 bv = *(const bf16x8*)(cur + (kk * 4 + quad) * 2048 +
                                     (wc * 128 + nt * 16 + l16) * 8);
        acc[0][nt] = MFMA16(af[0][kk], bv, acc[0][nt]);
        acc[1][nt] = MFMA16(af[1][kk], bv, acc[1][nt]);
      }
    // commit next chunk to the other buffer, one barrier
    if (kc < 15) {
#pragma unroll
      for (int i = 0; i < 4; ++i) *(bf16x8*)(nxt + (i * 512 + t) * 8) = stg[i];
    }
    __syncthreads();
  }

  // Z partials (reduce over quads; col-wave 0 owns the write)
#pragma unroll
  for (int mt = 0; mt < 2; ++mt) {
    float z = zacc[mt];
    z += __shfl_xor(z, 16);
    z += __shfl_xor(z, 32);
    if (wc == 0 && quad == 0)
      zpart[(size_t)sp * 8192 + g0 + wr * 32 + mt * 16 + l16] = z;
  }

  // epilogue: stage C tile (128x256 bf16, stride 264) in LDS, coalesced 16B writes
  __bf16* ctile = (__bf16*)smem;   // aliases vt+ls (both dead)
#pragma unroll
  for (int mt = 0; mt < 2; ++mt)
#pragma unroll
    for (int nt = 0; nt < 8; ++nt) {
      const int r0 = wr * 32 + mt * 16 + quad * 4;
      const int c  = wc * 128 + nt * 16 + l16;
#pragma unroll
      for (int rr = 0; rr < 4; ++rr)
        ctile[(r0 + rr) * 264 + c] = (__bf16)acc[mt][nt][rr];
    }
  __syncthreads();
  __bf16* pb = part + (size_t)sp * (8192 * 256);
#pragma unroll
  for (int p = 0; p < 8; ++p) {
    const int u = p * 512 + t;
    const int row = u >> 5, seg = u & 31;
    *(bf16x8*)(pb + (size_t)(g0 + row) * 256 + seg * 8) =
        *(const bf16x8*)(ctile + row * 264 + seg * 8);
  }
}

// ------- fused fixup + output GEMM: out = ((sum_s part[s]) / Z) @ Wo (fp32)
// grid (256): 32-row blocks. 4 waves 2x2 (16 rows x 128 cols each). No LDS.
__global__ __launch_bounds__(256) void k_outfix(const __bf16* __restrict__ part,
                                                const float* __restrict__ zpart,
                                                const __bf16* __restrict__ Wot,
                                                float* __restrict__ out) {
  const int t = threadIdx.x;
  const int lane = t & 63, w = t >> 6;
  const int l16 = lane & 15, quad = lane >> 4;
  const int wr = w >> 1, wc = w & 1;
  const int rb = blockIdx.x;
  const int arow = rb * 32 + wr * 16 + l16;
  float z = 0.f;
#pragma unroll
  for (int s = 0; s < 4; ++s) z += zpart[(size_t)s * 8192 + arow];
  const float iz = 1.0f / z;
  f32x4 acc[8] = {};
#pragma unroll 2
  for (int ks = 0; ks < 8; ++ks) {
    const int k0 = ks * 32 + quad * 8;
    float sum[8] = {};
#pragma unroll
    for (int s = 0; s < 4; ++s) {
      bf16x8 p = *(const bf16x8*)(part + (size_t)s * (8192 * 256) + (size_t)arow * 256 + k0);
#pragma unroll
      for (int j = 0; j < 8; ++j) sum[j] += (float)p[j];
    }
    bf16x8 afr;
#pragma unroll
    for (int j = 0; j < 8; ++j) afr[j] = (__bf16)(sum[j] * iz);
#pragma unroll
    for (int nt = 0; nt < 8; ++nt) {
      bf16x8 bv = *(const bf16x8*)(Wot + (size_t)(wc * 128 + nt * 16 + l16) * 256 + k0);
      acc[nt] = MFMA16(afr, bv, acc[nt]);
    }
  }
#pragma unroll
  for (int nt = 0; nt < 8; ++nt) {
    const int col = wc * 128 + nt * 16 + l16;
    const int r0  = rb * 32 + wr * 16 + quad * 4;
#pragma unroll
    for (int rr = 0; rr < 4; ++rr)
      out[(size_t)(r0 + rr) * 256 + col] = acc[nt][rr];
  }
}

extern "C" void kernel_launch(void* const* d_in, const int* in_sizes, int n_in,
                              void* d_out, int out_size, void* d_ws, size_t ws_size,
                              hipStream_t stream) {
  const float* x  = (const float*)d_in[0];
  const float* Wl = (const float*)d_in[1];
  const float* Wr = (const float*)d_in[2];
  const float* Wv = (const float*)d_in[3];
  const float* Wo = (const float*)d_in[4];
  char* ws = (char*)d_ws;
  __bf16* Wvt = (__bf16*)(ws + OFF_WVT);
  __bf16* Wlt = (__bf16*)(ws + OFF_WLT);
  __bf16* Wrt = (__bf16*)(ws + OFF_WRT);
  __bf16* Wot = (__bf16*)(ws + OFF_WOT);
  __bf16* Vt  = (__bf16*)(ws + OFF_VT);
  float*  lb  = (float*)(ws + OFF_L);
  float*  rbf = (float*)(ws + OFF_R);
  __bf16* prt = (__bf16*)(ws + OFF_PART);
  float*  zp  = (float*)(ws + OFF_ZP);
  float*  out = (float*)d_out;

  k_prepw<<<640, 256, 0, stream>>>(Wv, Wl, Wr, Wo, Wvt, Wlt, Wrt, Wot);
  k_proj<<<dim3(128, 6), 256, 0, stream>>>(x, Wvt, Wlt, Wrt, Vt, lb, rbf);
  k_attn<<<dim3(64, 4), 512, 0, stream>>>(lb, rbf, Vt, prt, zp);
  k_outfix<<<256, 256, 0, stream>>>(prt, zp, Wot, out);
}